// Round 9
// baseline (29.635 us; speedup 1.0000x reference)
//
#include <hip/hip_runtime.h>

typedef _Float16 f16x8 __attribute__((ext_vector_type(8)));
typedef _Float16 f16x4 __attribute__((ext_vector_type(4)));
typedef __fp16 fp16x2 __attribute__((ext_vector_type(2)));
typedef float f32x4 __attribute__((ext_vector_type(4)));

#define IMG 512
#define NB 32
#define OUTC 118
#define OUTR 32
#define GX 5
#define GY 16
#define NBLK (GX*GY*NB)    /* 2560 */
#define INSTR 32           /* per-strip lds_in slot stride (fp16): 64B rows */
#define VSTR 136           /* lds_v row stride (fp16): 272B, 2-way free */
#define VOFF (16*VSTR)

// sigma=1.5, 11-tap normalized Gaussian (validated R1-R8, absmax 0.0)
#define GW_LIST { 0.0010283804f, 0.0075987583f, 0.0360007700f, 0.1093606900f, \
  0.2130055300f, 0.2660117200f, 0.2130055300f, 0.1093606900f, 0.0360007700f, \
  0.0075987583f, 0.0010283804f }

__global__ __launch_bounds__(256, 4) void ssim_mfma(const float* __restrict__ img1,
                                                    const float* __restrict__ img2,
                                                    float* __restrict__ partials) {
    // one strip of input (26 real slots + 6 zero), col-major per column, fp16
    __shared__ _Float16 lds_in[2][128][INSTR];           // 16.4 KB
    // v-conv output V[row][col], row-major fp16 (+32 tail for xx=7 overflow reads)
    __shared__ _Float16 lds_v[5*VOFF + 32];              // 21.8 KB
    __shared__ _Float16 gwt[64];
    __shared__ float red[4];

    const int tid  = threadIdx.x;
    const int lane = tid & 63;
    const int lm   = lane & 15;
    const int kg   = lane >> 4;
    const int w    = tid >> 6;

    const int bx = blockIdx.x, by = blockIdx.y, bz = blockIdx.z;
    const float* __restrict__ p1 = img1 + (size_t)bz * (IMG*IMG);
    const float* __restrict__ p2 = img2 + (size_t)bz * (IMG*IMG);
    const int x0 = bx * OUTC;
    const int y0 = by * OUTR;

    // staging ids: 128 cols x 2 slot-halves (16 slots each; real slots < 26)
    const int ci = tid & 127;
    const int hh = tid >> 7;
    const int gc = x0 - 5 + ci;
    const bool okc = (gc >= 0) && (gc < IMG);
    const int gcc  = okc ? gc : 0;
    const int slot0 = hh * 16;

    typedef union { fp16x2 p2v[8]; f16x8 v[2]; } pack16;

    // load one strip (rows ybase..ybase+25, zero-padded) into packed regs
    auto load_strip = [&](int ybase, pack16& ua, pack16& ub) {
#pragma unroll
        for (int pp = 0; pp < 8; ++pp) {
            const int s0 = slot0 + 2*pp;
            const int ar0 = ybase + s0;
            const int ar1 = ar0 + 1;
            const bool ok0 = okc & (s0   < 26) & (ar0 >= 0) & (ar0 < IMG);
            const bool ok1 = okc & (s0+1 < 26) & (ar1 >= 0) & (ar1 < IMG);
            const int i0 = ok0 ? ar0 : 0, i1 = ok1 ? ar1 : 0;
            float a0 = p1[i0*IMG + gcc], a1 = p1[i1*IMG + gcc];
            float b0 = p2[i0*IMG + gcc], b1 = p2[i1*IMG + gcc];
            a0 = ok0 ? a0 : 0.f;  a1 = ok1 ? a1 : 0.f;
            b0 = ok0 ? b0 : 0.f;  b1 = ok1 ? b1 : 0.f;
            ua.p2v[pp] = __builtin_amdgcn_cvt_pkrtz(a0, a1);
            ub.p2v[pp] = __builtin_amdgcn_cvt_pkrtz(b0, b1);
        }
    };
    auto write_strip = [&](pack16& ua, pack16& ub) {
        *(f16x8*)&lds_in[0][ci][slot0]     = ua.v[0];
        *(f16x8*)&lds_in[0][ci][slot0 + 8] = ua.v[1];
        *(f16x8*)&lds_in[1][ci][slot0]     = ub.v[0];
        *(f16x8*)&lds_in[1][ci][slot0 + 8] = ub.v[1];
    };

    // ---- strip-0 staging ----
    {
        pack16 ua, ub;
        load_strip(y0 - 5, ua, ub);
        write_strip(ua, ub);
    }
    // ---- gaussian table + lds_v pad/tail zeroing (keeps stray reads finite) ----
    {
        const float GWc[11] = GW_LIST;
        if (tid < 64) {
            float wv = 0.f;
            const int t = tid - 16;
#pragma unroll
            for (int k = 0; k < 11; ++k) if (t == k) wv = GWc[k];
            gwt[tid] = (_Float16)wv;
        }
        f16x8 z = {};
        if (tid >= 64 && tid < 144) {          // 80 pad rows: cols 128..135
            const int u = tid - 64;
            const int f = u / 16, r = u % 16;
            *(f16x8*)&lds_v[f*VOFF + r*VSTR + 128] = z;
        } else if (tid >= 144 && tid < 148) {  // 32-elem tail
            *(f16x8*)&lds_v[5*VOFF + (tid-144)*8] = z;
        }
    }
    __syncthreads();

    // banded weight fragment: serves as B[k][n]=GW[k-n] for BOTH conv stages
    union { _Float16 h[8]; f16x8 v; } wu;
#pragma unroll
    for (int i = 0; i < 8; ++i) wu.h[i] = gwt[16 + kg*8 + i - lm];

    float local = 0.f;
    const f32x4 zc = {0.f, 0.f, 0.f, 0.f};

    // stage V: A = X^T (data, b128 from col-major lds_in), B = weights.
    // D[m=col][n=out_row]: lane holds out_row=lm, cols kg*4+j  -> one b64 per field
    auto stage_v = [&]() {
#pragma unroll
        for (int q = 0; q < 2; ++q) {
            const int cb = 2*w + q;
            const f16x8 xf = *(const f16x8*)&lds_in[0][cb*16 + lm][kg*8];
            const f16x8 yf = *(const f16x8*)&lds_in[1][cb*16 + lm][kg*8];
            const f16x8 fr0 = xf, fr1 = yf;
            const f16x8 fr2 = xf*xf, fr3 = yf*yf, fr4 = xf*yf;
            const int cbase = cb*16 + kg*4;
#define DO_F(F, FR) { \
            const f32x4 d = __builtin_amdgcn_mfma_f32_16x16x32_f16(FR, wu.v, zc, 0, 0, 0); \
            union { fp16x2 p[2]; f16x4 v4; } pk; \
            pk.p[0] = __builtin_amdgcn_cvt_pkrtz(d[0], d[1]); \
            pk.p[1] = __builtin_amdgcn_cvt_pkrtz(d[2], d[3]); \
            *(f16x4*)&lds_v[(F)*VOFF + lm*VSTR + cbase] = pk.v4; }
            DO_F(0, fr0) DO_F(1, fr1) DO_F(2, fr2) DO_F(3, fr3) DO_F(4, fr4)
#undef DO_F
        }
    };

    // stage H: A = V rows (b128, k=cols contiguous), B = weights; + SSIM map
    auto stage_h = [&]() {
#pragma unroll
        for (int q = 0; q < 2; ++q) {
            const int xx = 2*w + q;
            const int cb2 = xx*16 + kg*8;
            const f16x8 a0 = *(const f16x8*)&lds_v[0*VOFF + lm*VSTR + cb2];
            const f16x8 a1 = *(const f16x8*)&lds_v[1*VOFF + lm*VSTR + cb2];
            const f16x8 a2 = *(const f16x8*)&lds_v[2*VOFF + lm*VSTR + cb2];
            const f16x8 a3 = *(const f16x8*)&lds_v[3*VOFF + lm*VSTR + cb2];
            const f16x8 a4 = *(const f16x8*)&lds_v[4*VOFF + lm*VSTR + cb2];
            const f32x4 d0 = __builtin_amdgcn_mfma_f32_16x16x32_f16(a0, wu.v, zc, 0,0,0);
            const f32x4 d1 = __builtin_amdgcn_mfma_f32_16x16x32_f16(a1, wu.v, zc, 0,0,0);
            const f32x4 d2 = __builtin_amdgcn_mfma_f32_16x16x32_f16(a2, wu.v, zc, 0,0,0);
            const f32x4 d3 = __builtin_amdgcn_mfma_f32_16x16x32_f16(a3, wu.v, zc, 0,0,0);
            const f32x4 d4 = __builtin_amdgcn_mfma_f32_16x16x32_f16(a4, wu.v, zc, 0,0,0);
            const int X = xx*16 + lm;
            const bool valid = (X < OUTC) & (x0 + X < IMG);
            float s4 = 0.f;
#pragma unroll
            for (int j = 0; j < 4; ++j) {
                const float mu1 = d0[j], mu2 = d1[j];
                const float m11 = mu1*mu1, m22 = mu2*mu2, m12 = mu1*mu2;
                const float s1 = d2[j] - m11, s2 = d3[j] - m22, sx = d4[j] - m12;
                const float num = (2.f*m12 + 1e-4f) * (2.f*sx + 9e-4f);
                const float den = (m11 + m22 + 1e-4f) * (s1 + s2 + 9e-4f);
                s4 += num * __builtin_amdgcn_rcpf(den);
            }
            local += valid ? s4 : 0.f;
        }
    };

    // ================= strip 0 (out rows y0..y0+15) =================
    stage_v();
    __syncthreads();                 // V0 done reading lds_in

    // strip-1 load issued EARLY (HBM latency hides under H0 compute)
    pack16 ua1, ub1;
    load_strip(y0 + 11, ua1, ub1);   // rows y0+11 .. y0+36

    stage_h();

    write_strip(ua1, ub1);           // safe: all waves past V0 barrier
    __syncthreads();                 // strip-1 visible

    // ================= strip 1 (out rows y0+16..y0+31) ==============
    stage_v();
    __syncthreads();
    stage_h();

    // ---- block reduction ----
#pragma unroll
    for (int off = 32; off > 0; off >>= 1)
        local += __shfl_down(local, off, 64);
    if (lane == 0) red[w] = local;
    __syncthreads();
    if (tid == 0) {
        partials[(size_t)((bz*GY + by)*GX + bx)] = red[0] + red[1] + red[2] + red[3];
    }
}

__global__ __launch_bounds__(256) void ssim_finalize(const float* __restrict__ partials,
                                                     float* __restrict__ out) {
    __shared__ double red[4];
    double s = 0.0;
    // 2560 partials = 640 float4
    for (int i = threadIdx.x; i < NBLK/4; i += 256) {
        const float4 v = reinterpret_cast<const float4*>(partials)[i];
        s += (double)v.x + (double)v.y + (double)v.z + (double)v.w;
    }
#pragma unroll
    for (int off = 32; off > 0; off >>= 1)
        s += __shfl_down(s, off, 64);
    if ((threadIdx.x & 63) == 0) red[threadIdx.x >> 6] = s;
    __syncthreads();
    if (threadIdx.x == 0) {
        double tot = red[0] + red[1] + red[2] + red[3];
        out[0] = (float)(1.0 - tot / (32.0 * 512.0 * 512.0));
    }
}

extern "C" void kernel_launch(void* const* d_in, const int* in_sizes, int n_in,
                              void* d_out, int out_size, void* d_ws, size_t ws_size,
                              hipStream_t stream) {
    const float* img1 = (const float*)d_in[0];
    const float* img2 = (const float*)d_in[1];
    float* out = (float*)d_out;
    float* partials = (float*)d_ws;

    dim3 grid(GX, GY, NB);   // 5 x 16 x 32 = 2560 blocks
    ssim_mfma<<<grid, 256, 0, stream>>>(img1, img2, partials);
    ssim_finalize<<<1, 256, 0, stream>>>(partials, out);
}

// Round 11
// 28.251 us; speedup vs baseline: 1.0490x; 1.0490x over previous
//
#include <hip/hip_runtime.h>

typedef _Float16 f16x8 __attribute__((ext_vector_type(8)));
typedef _Float16 f16x4 __attribute__((ext_vector_type(4)));
typedef __fp16 fp16x2 __attribute__((ext_vector_type(2)));
typedef float f32x4 __attribute__((ext_vector_type(4)));

#define IMG 512
#define NB 32
#define OUTC 118
#define OUTR 32
#define GX 5
#define GY 16
#define NBLK (GX*GY*NB)    /* 2560 */
#define INSTR 48           /* lds_in slot stride (fp16) */
#define IOFF (128*INSTR)   /* 6144 f16 per image plane */
#define VSTR 136           /* v-buffer row stride (fp16) */
#define VOFF (16*VSTR)     /* 2176 f16 per field */
#define VLEN (5*VOFF + 32) /* 10912 f16 incl tail */
#define BUF0 (2*IOFF)      /* buf0 at 12288; buf1 at 0 aliases dead lds_in */

// sigma=1.5, 11-tap normalized Gaussian (validated R1-R9, absmax 0.0)
#define GW_LIST { 0.0010283804f, 0.0075987583f, 0.0360007700f, 0.1093606900f, \
  0.2130055300f, 0.2660117200f, 0.2130055300f, 0.1093606900f, 0.0360007700f, \
  0.0075987583f, 0.0010283804f }

__global__ __launch_bounds__(256, 3) void ssim_mfma(const float* __restrict__ img1,
                                                    const float* __restrict__ img2,
                                                    float* __restrict__ partials) {
    // [0 .. 2*IOFF): staged input (col-major per column), fp16 — DEAD after V-compute
    // [0 .. VLEN):   buf1 (strip-1 V), aliased onto dead lds_in (pads = finite leftovers)
    // [BUF0 .. +VLEN): buf0 (strip-0 V); pads/tail MUST be zeroed (uninit LDS can be NaN:
    //                  0-weight x NaN = NaN poisons MFMA rows — R10 lesson)
    __shared__ _Float16 smem[BUF0 + VLEN];   // 46,400 B -> 3 blocks/CU
    __shared__ _Float16 gwt[64];
    __shared__ float red[4];

    const int tid  = threadIdx.x;
    const int lane = tid & 63;
    const int lm   = lane & 15;
    const int kg   = lane >> 4;
    const int w    = tid >> 6;

    const int bx = blockIdx.x, by = blockIdx.y, bz = blockIdx.z;
    const float* __restrict__ p1 = img1 + (size_t)bz * (IMG*IMG);
    const float* __restrict__ p2 = img2 + (size_t)bz * (IMG*IMG);
    const int x0 = bx * OUTC;
    const int y0 = by * OUTR;

    // staging ids: 128 cols x 2 slot-halves (24 slots each)
    const int ci = tid & 127;
    const int hh = tid >> 7;
    const int gc = x0 - 5 + ci;
    const bool okc = (gc >= 0) && (gc < IMG);
    const int gcc  = okc ? gc : 0;

    // ---- single-pass staging: 42 real rows (y0-5 .. y0+36), slots 42..47 zero ----
    {
        union { fp16x2 p2v[12]; f16x8 v[3]; } ua, ub;
        const int slot0 = hh * 24;
#pragma unroll
        for (int pp = 0; pp < 12; ++pp) {
            const int s0 = slot0 + 2*pp;
            const int ar0 = y0 - 5 + s0;
            const int ar1 = ar0 + 1;
            const bool ok0 = okc & (s0   < 42) & (ar0 >= 0) & (ar0 < IMG);
            const bool ok1 = okc & (s0+1 < 42) & (ar1 >= 0) & (ar1 < IMG);
            const int i0 = ok0 ? ar0 : 0, i1 = ok1 ? ar1 : 0;
            float a0 = p1[i0*IMG + gcc], a1 = p1[i1*IMG + gcc];
            float b0 = p2[i0*IMG + gcc], b1 = p2[i1*IMG + gcc];
            a0 = ok0 ? a0 : 0.f;  a1 = ok1 ? a1 : 0.f;
            b0 = ok0 ? b0 : 0.f;  b1 = ok1 ? b1 : 0.f;
            ua.p2v[pp] = __builtin_amdgcn_cvt_pkrtz(a0, a1);
            ub.p2v[pp] = __builtin_amdgcn_cvt_pkrtz(b0, b1);
        }
        _Float16* dst = &smem[ci*INSTR + slot0];
#pragma unroll
        for (int m = 0; m < 3; ++m) {
            *(f16x8*)(dst + 8*m)        = ua.v[m];
            *(f16x8*)(dst + IOFF + 8*m) = ub.v[m];
        }
    }
    // ---- gaussian band table + buf0 pad/tail zeroing ----
    {
        const float GWc[11] = GW_LIST;
        if (tid < 64) {
            float wv = 0.f;
            const int t = tid - 16;
#pragma unroll
            for (int k = 0; k < 11; ++k) if (t == k) wv = GWc[k];
            gwt[tid] = (_Float16)wv;
        }
        f16x8 z = {};
        if (tid >= 64 && tid < 144) {          // buf0 pads: cols 128..135, 5 fields x 16 rows
            const int u = tid - 64;
            const int f = u / 16, r = u % 16;
            *(f16x8*)&smem[BUF0 + f*VOFF + r*VSTR + 128] = z;
        } else if (tid >= 144 && tid < 148) {  // buf0 32-elem tail
            *(f16x8*)&smem[BUF0 + 5*VOFF + (tid-144)*8] = z;
        }
    }
    __syncthreads();

    // banded weight fragment: B[k][n]=GW[k-n], serves BOTH conv stages
    union { _Float16 h[8]; f16x8 v; } wu;
#pragma unroll
    for (int i = 0; i < 8; ++i) wu.h[i] = gwt[16 + kg*8 + i - lm];

    const f32x4 zc = {0.f, 0.f, 0.f, 0.f};

    // ---- V-compute, BOTH strips, results packed into registers ----
    // A = X^T (b128 from col-major lds_in), B = weights.
    // lane holds V[row lm][cols cb*16+kg*4 .. +3] per field as f16x4.
    f16x4 pk[2][2][5];
#pragma unroll
    for (int s = 0; s < 2; ++s) {
#pragma unroll
        for (int q = 0; q < 2; ++q) {
            const int cb = 2*w + q;
            const _Float16* colp = &smem[(cb*16 + lm)*INSTR + s*16 + kg*8];
            const f16x8 xf = *(const f16x8*)colp;
            const f16x8 yf = *(const f16x8*)(colp + IOFF);
            const f16x8 fr[5] = { xf, yf, xf*xf, yf*yf, xf*yf };
#pragma unroll
            for (int f = 0; f < 5; ++f) {
                const f32x4 d = __builtin_amdgcn_mfma_f32_16x16x32_f16(fr[f], wu.v, zc, 0, 0, 0);
                union { fp16x2 p[2]; f16x4 v4; } c;
                c.p[0] = __builtin_amdgcn_cvt_pkrtz(d[0], d[1]);
                c.p[1] = __builtin_amdgcn_cvt_pkrtz(d[2], d[3]);
                pk[s][q][f] = c.v4;
            }
        }
    }

    // ---- strip-0 V -> buf0 (no alias with lds_in) ----
    {
        _Float16* b = &smem[BUF0 + lm*VSTR + 2*w*16 + kg*4];
#pragma unroll
        for (int q = 0; q < 2; ++q)
#pragma unroll
            for (int f = 0; f < 5; ++f)
                *(f16x4*)(b + f*VOFF + q*16) = pk[0][q][f];
    }
    __syncthreads();   // all V-computes done (lds_in dead), buf0 ready

    // ---- phase A: strip-1 V -> buf1 (aliased)  ||  H0 from buf0 ----
    {
        _Float16* b = &smem[lm*VSTR + 2*w*16 + kg*4];
#pragma unroll
        for (int q = 0; q < 2; ++q)
#pragma unroll
            for (int f = 0; f < 5; ++f)
                *(f16x4*)(b + f*VOFF + q*16) = pk[1][q][f];
    }

    float local = 0.f;
    // H: A = V rows (b128, k=cols contiguous), B = weights; + SSIM map.
    // Pad reads (cols 128+) carry zero band weight; zeroed (buf0) / finite (buf1).
    auto stage_h = [&](int base) {
#pragma unroll
        for (int q = 0; q < 2; ++q) {
            const int xx = 2*w + q;
            const _Float16* vp = &smem[base + lm*VSTR + xx*16 + kg*8];
            f32x4 d[5];
#pragma unroll
            for (int f = 0; f < 5; ++f) {
                const f16x8 a = *(const f16x8*)(vp + f*VOFF);
                d[f] = __builtin_amdgcn_mfma_f32_16x16x32_f16(a, wu.v, zc, 0, 0, 0);
            }
            const int X = xx*16 + lm;
            const bool valid = (X < OUTC) & (x0 + X < IMG);
            float s4 = 0.f;
#pragma unroll
            for (int j = 0; j < 4; ++j) {
                const float mu1 = d[0][j], mu2 = d[1][j];
                const float m11 = mu1*mu1, m22 = mu2*mu2, m12 = mu1*mu2;
                const float s1 = d[2][j] - m11, s2 = d[3][j] - m22, sx = d[4][j] - m12;
                const float num = (2.f*m12 + 1e-4f) * (2.f*sx + 9e-4f);
                const float den = (m11 + m22 + 1e-4f) * (s1 + s2 + 9e-4f);
                s4 += num * __builtin_amdgcn_rcpf(den);
            }
            local += valid ? s4 : 0.f;
        }
    };

    stage_h(BUF0);     // overlaps with buf1 writes (independent LDS regions)
    __syncthreads();   // buf1 writes visible
    stage_h(0);        // strip 1

    // ---- block reduction ----
#pragma unroll
    for (int off = 32; off > 0; off >>= 1)
        local += __shfl_down(local, off, 64);
    if (lane == 0) red[w] = local;
    __syncthreads();
    if (tid == 0) {
        partials[(size_t)((bz*GY + by)*GX + bx)] = red[0] + red[1] + red[2] + red[3];
    }
}

__global__ __launch_bounds__(256) void ssim_finalize(const float* __restrict__ partials,
                                                     float* __restrict__ out) {
    __shared__ double red[4];
    double s = 0.0;
    // 2560 partials = 640 float4
    for (int i = threadIdx.x; i < NBLK/4; i += 256) {
        const float4 v = reinterpret_cast<const float4*>(partials)[i];
        s += (double)v.x + (double)v.y + (double)v.z + (double)v.w;
    }
#pragma unroll
    for (int off = 32; off > 0; off >>= 1)
        s += __shfl_down(s, off, 64);
    if ((threadIdx.x & 63) == 0) red[threadIdx.x >> 6] = s;
    __syncthreads();
    if (threadIdx.x == 0) {
        double tot = red[0] + red[1] + red[2] + red[3];
        out[0] = (float)(1.0 - tot / (32.0 * 512.0 * 512.0));
    }
}

extern "C" void kernel_launch(void* const* d_in, const int* in_sizes, int n_in,
                              void* d_out, int out_size, void* d_ws, size_t ws_size,
                              hipStream_t stream) {
    const float* img1 = (const float*)d_in[0];
    const float* img2 = (const float*)d_in[1];
    float* out = (float*)d_out;
    float* partials = (float*)d_ws;

    dim3 grid(GX, GY, NB);   // 5 x 16 x 32 = 2560 blocks
    ssim_mfma<<<grid, 256, 0, stream>>>(img1, img2, partials);
    ssim_finalize<<<1, 256, 0, stream>>>(partials, out);
}

// Round 12
// 25.808 us; speedup vs baseline: 1.1483x; 1.0946x over previous
//
#include <hip/hip_runtime.h>

typedef _Float16 f16x8 __attribute__((ext_vector_type(8)));
typedef _Float16 f16x4 __attribute__((ext_vector_type(4)));
typedef __fp16 fp16x2 __attribute__((ext_vector_type(2)));
typedef float f32x4 __attribute__((ext_vector_type(4)));

#define IMG 512
#define NB 32
#define OUTC 118
#define OUTR 32
#define GX 5
#define GY 16
#define NBLK (GX*GY*NB)    /* 2560 = 8 * 320: bijective XCD swizzle OK */
#define INSTR 48           /* lds_in slot stride (fp16) */
#define IOFF (128*INSTR)   /* 6144 f16 per image plane */
#define VSTR 136           /* v-buffer row stride (fp16) */
#define VOFF (16*VSTR)     /* 2176 f16 per field */
#define VLEN (5*VOFF + 32) /* incl tail */
#define BUF0 (2*IOFF)      /* buf0 after staged input; buf1 at 0 aliases dead lds_in */

// sigma=1.5, 11-tap normalized Gaussian (validated R1-R11, absmax 0.0)
#define GW_LIST { 0.0010283804f, 0.0075987583f, 0.0360007700f, 0.1093606900f, \
  0.2130055300f, 0.2660117200f, 0.2130055300f, 0.1093606900f, 0.0360007700f, \
  0.0075987583f, 0.0010283804f }

__global__ __launch_bounds__(256, 3) void ssim_mfma(const float* __restrict__ img1,
                                                    const float* __restrict__ img2,
                                                    float* __restrict__ partials) {
    // [0 .. 2*IOFF): staged input (col-major per column), fp16 — DEAD after V-compute
    // [0 .. VLEN):   buf1 (strip-1 V), aliased onto dead lds_in (pads = finite leftovers)
    // [BUF0..+VLEN): buf0 (strip-0 V); pads/tail zeroed (uninit LDS may be NaN — R10)
    __shared__ _Float16 smem[BUF0 + VLEN];   // 46,400 B -> 3 blocks/CU
    __shared__ float red[4];

    const int tid  = threadIdx.x;
    const int lane = tid & 63;
    const int lm   = lane & 15;
    const int kg   = lane >> 4;
    const int w    = tid >> 6;

    // ---- bijective XCD swizzle: consecutive work-ids share halos -> same XCD L2 ----
    const int d   = (blockIdx.z * GY + blockIdx.y) * GX + blockIdx.x;  // dispatch id
    const int wid = (d & 7) * (NBLK / 8) + (d >> 3);                   // work id
    const int bx  = wid % GX;
    const int t2  = wid / GX;
    const int by  = t2 % GY;
    const int bz  = t2 / GY;

    const float* __restrict__ p1 = img1 + (size_t)bz * (IMG*IMG);
    const float* __restrict__ p2 = img2 + (size_t)bz * (IMG*IMG);
    const int x0 = bx * OUTC;
    const int y0 = by * OUTR;

    // ---- banded weight fragment WITHOUT LDS (no barrier dependency) ----
    // wu.h[i] = GW[kg*8 + i - lm] (0 outside band), via ds_bpermute from lane table
    union { fp16x2 p[4]; f16x8 v; } wu;
    {
        const float GWc[11] = GW_LIST;
        float gf = 0.f;
#pragma unroll
        for (int k = 0; k < 11; ++k) gf = (lane == k) ? GWc[k] : gf;
        const int gi = __float_as_int(gf);
        float hv[8];
#pragma unroll
        for (int i = 0; i < 8; ++i) {
            const int t = kg*8 + i - lm;
            const int bp = __builtin_amdgcn_ds_bpermute(t * 4, gi);
            hv[i] = ((unsigned)t < 11u) ? __int_as_float(bp) : 0.f;
        }
#pragma unroll
        for (int j = 0; j < 4; ++j)
            wu.p[j] = __builtin_amdgcn_cvt_pkrtz(hv[2*j], hv[2*j+1]);
    }

    // ---- per-wave staging: wave w owns staged cols [32w, 32w+32), all 48 slots ----
    // (exactly the columns its own V-MFMAs read -> NO barrier between stage and V)
    {
        const int cl   = lane & 31;
        const int half = lane >> 5;
        const int ci   = w*32 + cl;
        const int gc   = x0 - 5 + ci;
        const bool okc = (gc >= 0) && (gc < IMG);
        const int gcc  = okc ? gc : 0;
        const int slot0 = half * 24;

        union { fp16x2 p2v[12]; f16x8 v[3]; } ua, ub;
#pragma unroll
        for (int pp = 0; pp < 12; ++pp) {
            const int s0 = slot0 + 2*pp;
            const int ar0 = y0 - 5 + s0;
            const int ar1 = ar0 + 1;
            const bool ok0 = okc & (s0   < 42) & (ar0 >= 0) & (ar0 < IMG);
            const bool ok1 = okc & (s0+1 < 42) & (ar1 >= 0) & (ar1 < IMG);
            const int i0 = ok0 ? ar0 : 0, i1 = ok1 ? ar1 : 0;
            float a0 = p1[i0*IMG + gcc], a1 = p1[i1*IMG + gcc];
            float b0 = p2[i0*IMG + gcc], b1 = p2[i1*IMG + gcc];
            a0 = ok0 ? a0 : 0.f;  a1 = ok1 ? a1 : 0.f;
            b0 = ok0 ? b0 : 0.f;  b1 = ok1 ? b1 : 0.f;
            ua.p2v[pp] = __builtin_amdgcn_cvt_pkrtz(a0, a1);
            ub.p2v[pp] = __builtin_amdgcn_cvt_pkrtz(b0, b1);
        }
        _Float16* dst = &smem[ci*INSTR + slot0];
#pragma unroll
        for (int m = 0; m < 3; ++m) {
            *(f16x8*)(dst + 8*m)        = ua.v[m];
            *(f16x8*)(dst + IOFF + 8*m) = ub.v[m];
        }
    }

    const f32x4 zc = {0.f, 0.f, 0.f, 0.f};

    // ---- V-compute, BOTH strips, from own wave's staged columns (wave-local) ----
    f16x4 pk[2][2][5];
#pragma unroll
    for (int s = 0; s < 2; ++s) {
#pragma unroll
        for (int q = 0; q < 2; ++q) {
            const int cb = 2*w + q;
            const _Float16* colp = &smem[(cb*16 + lm)*INSTR + s*16 + kg*8];
            const f16x8 xf = *(const f16x8*)colp;
            const f16x8 yf = *(const f16x8*)(colp + IOFF);
            const f16x8 fr[5] = { xf, yf, xf*xf, yf*yf, xf*yf };
#pragma unroll
            for (int f = 0; f < 5; ++f) {
                const f32x4 dd = __builtin_amdgcn_mfma_f32_16x16x32_f16(fr[f], wu.v, zc, 0, 0, 0);
                union { fp16x2 p[2]; f16x4 v4; } c;
                c.p[0] = __builtin_amdgcn_cvt_pkrtz(dd[0], dd[1]);
                c.p[1] = __builtin_amdgcn_cvt_pkrtz(dd[2], dd[3]);
                pk[s][q][f] = c.v4;
            }
        }
    }

    // ---- strip-0 V -> buf0 + pad/tail zeroing ----
    {
        _Float16* b = &smem[BUF0 + lm*VSTR + 2*w*16 + kg*4];
#pragma unroll
        for (int q = 0; q < 2; ++q)
#pragma unroll
            for (int f = 0; f < 5; ++f)
                *(f16x4*)(b + f*VOFF + q*16) = pk[0][q][f];

        f16x8 z = {};
        if (tid < 80) {                         // buf0 pads: cols 128..135, 5 fields x 16 rows
            const int f = tid / 16, r = tid % 16;
            *(f16x8*)&smem[BUF0 + f*VOFF + r*VSTR + 128] = z;
        } else if (tid < 84) {                  // buf0 32-elem tail
            *(f16x8*)&smem[BUF0 + 5*VOFF + (tid-80)*8] = z;
        }
    }
    __syncthreads();   // all V-computes done (lds_in dead), buf0 ready

    // ---- strip-1 V -> buf1 (aliased)  ||  H0 from buf0 ----
    {
        _Float16* b = &smem[lm*VSTR + 2*w*16 + kg*4];
#pragma unroll
        for (int q = 0; q < 2; ++q)
#pragma unroll
            for (int f = 0; f < 5; ++f)
                *(f16x4*)(b + f*VOFF + q*16) = pk[1][q][f];
    }

    float local = 0.f;
    // H: A = V rows (b128, k=cols contiguous), B = weights; + SSIM map.
    auto stage_h = [&](int base) {
#pragma unroll
        for (int q = 0; q < 2; ++q) {
            const int xx = 2*w + q;
            const _Float16* vp = &smem[base + lm*VSTR + xx*16 + kg*8];
            f32x4 dd[5];
#pragma unroll
            for (int f = 0; f < 5; ++f) {
                const f16x8 a = *(const f16x8*)(vp + f*VOFF);
                dd[f] = __builtin_amdgcn_mfma_f32_16x16x32_f16(a, wu.v, zc, 0, 0, 0);
            }
            const int X = xx*16 + lm;
            const bool valid = (X < OUTC) & (x0 + X < IMG);
            float s4 = 0.f;
#pragma unroll
            for (int j = 0; j < 4; ++j) {
                const float mu1 = dd[0][j], mu2 = dd[1][j];
                const float m11 = mu1*mu1, m22 = mu2*mu2, m12 = mu1*mu2;
                const float s1 = dd[2][j] - m11, s2 = dd[3][j] - m22, sx = dd[4][j] - m12;
                const float num = (2.f*m12 + 1e-4f) * (2.f*sx + 9e-4f);
                const float den = (m11 + m22 + 1e-4f) * (s1 + s2 + 9e-4f);
                s4 += num * __builtin_amdgcn_rcpf(den);
            }
            local += valid ? s4 : 0.f;
        }
    };

    stage_h(BUF0);     // overlaps with buf1 writes (independent LDS regions)
    __syncthreads();   // buf1 writes visible
    stage_h(0);        // strip 1

    // ---- block reduction ----
#pragma unroll
    for (int off = 32; off > 0; off >>= 1)
        local += __shfl_down(local, off, 64);
    if (lane == 0) red[w] = local;
    __syncthreads();
    if (tid == 0) {
        partials[(size_t)wid] = red[0] + red[1] + red[2] + red[3];
    }
}

__global__ __launch_bounds__(256) void ssim_finalize(const float* __restrict__ partials,
                                                     float* __restrict__ out) {
    __shared__ double red[4];
    double s = 0.0;
    // 2560 partials = 640 float4
    for (int i = threadIdx.x; i < NBLK/4; i += 256) {
        const float4 v = reinterpret_cast<const float4*>(partials)[i];
        s += (double)v.x + (double)v.y + (double)v.z + (double)v.w;
    }
#pragma unroll
    for (int off = 32; off > 0; off >>= 1)
        s += __shfl_down(s, off, 64);
    if ((threadIdx.x & 63) == 0) red[threadIdx.x >> 6] = s;
    __syncthreads();
    if (threadIdx.x == 0) {
        double tot = red[0] + red[1] + red[2] + red[3];
        out[0] = (float)(1.0 - tot / (32.0 * 512.0 * 512.0));
    }
}

extern "C" void kernel_launch(void* const* d_in, const int* in_sizes, int n_in,
                              void* d_out, int out_size, void* d_ws, size_t ws_size,
                              hipStream_t stream) {
    const float* img1 = (const float*)d_in[0];
    const float* img2 = (const float*)d_in[1];
    float* out = (float*)d_out;
    float* partials = (float*)d_ws;

    dim3 grid(GX, GY, NB);   // 5 x 16 x 32 = 2560 blocks
    ssim_mfma<<<grid, 256, 0, stream>>>(img1, img2, partials);
    ssim_finalize<<<1, 256, 0, stream>>>(partials, out);
}